// Round 1
// baseline (201.793 us; speedup 1.0000x reference)
//
#include <hip/hip_runtime.h>

typedef _Float16 h16;
typedef __attribute__((ext_vector_type(8))) _Float16 f16x8;
typedef __attribute__((ext_vector_type(4))) float f32x4;

#define S_LEN 4096
#define NHEAD 16
#define HDIM  64
#define WIN   128
#define TQ    128
#define NCH   9
#define VSTR  392   // f16 elems per V^T row (16B-aligned: 392*2=784=49*16)
#define SSTR  40    // f16 elems per P row   (40*2=80=5*16)

__global__ __launch_bounds__(512, 1)
void wattn(const float* __restrict__ Qg, const float* __restrict__ Kg,
           const float* __restrict__ Vg, float* __restrict__ Og)
{
    __shared__ h16 Vlds[HDIM * VSTR];      // V^T: [h][key-in-window], 50176 B
    __shared__ h16 Slds[8 * 16 * SSTR];    // per-wave P tile, 10240 B

    const int tid  = threadIdx.x;
    const int wid  = tid >> 6;
    const int lane = tid & 63;
    const int l15  = lane & 15;
    const int quad = lane >> 4;

    const int qt   = blockIdx.x;
    const int head = blockIdx.y;
    const int b    = blockIdx.z;

    const int q0    = qt * TQ;
    const int kbase = q0 - WIN;            // global key idx of window-rel 0
    const int rowstride = NHEAD * HDIM;    // 1024 floats between seq positions

    // ---------------- stage V^T into LDS (f32 -> f16, zeros outside [0,S)) ----
    // 192 key-pairs x 16 h-quads = 3072 tasks, 512 threads -> 6 passes
    for (int p = 0; p < 6; ++p) {
        int task = p * 512 + tid;
        int pair = task >> 4;              // 0..191
        int hq   = task & 15;              // 0..15
        int kr   = pair * 2;               // window-relative key (even)
        int h0   = hq * 4;
        int kg   = kbase + kr;
        float4 v0 = {0.f,0.f,0.f,0.f}, v1 = {0.f,0.f,0.f,0.f};
        if (kg >= 0 && kg < S_LEN)
            v0 = *(const float4*)(Vg + ((long)(b * S_LEN + kg) * NHEAD + head) * HDIM + h0);
        if (kg + 1 >= 0 && kg + 1 < S_LEN)
            v1 = *(const float4*)(Vg + ((long)(b * S_LEN + kg + 1) * NHEAD + head) * HDIM + h0);
        h16* dst = &Vlds[h0 * VSTR + kr];
        dst[0]        = (h16)v0.x; dst[1]        = (h16)v1.x;
        dst[VSTR]     = (h16)v0.y; dst[VSTR+1]   = (h16)v1.y;
        dst[2*VSTR]   = (h16)v0.z; dst[2*VSTR+1] = (h16)v1.z;
        dst[3*VSTR]   = (h16)v0.w; dst[3*VSTR+1] = (h16)v1.w;
    }

    // ---------------- Q fragments (scaled by h^-0.5), A-layout --------------
    // a-frag: Q[m = lane&15][k = quad*8 + j], two frags cover h=0..31, 32..63
    const int qrow = q0 + wid * 16 + l15;
    f16x8 aQ[2];
    {
        const float* qp = Qg + ((long)(b * S_LEN + qrow) * NHEAD + head) * HDIM;
        #pragma unroll
        for (int kk = 0; kk < 2; ++kk) {
            float4 x0 = *(const float4*)(qp + kk*32 + quad*8);
            float4 x1 = *(const float4*)(qp + kk*32 + quad*8 + 4);
            f16x8 a;
            a[0] = (h16)(x0.x * 0.125f); a[1] = (h16)(x0.y * 0.125f);
            a[2] = (h16)(x0.z * 0.125f); a[3] = (h16)(x0.w * 0.125f);
            a[4] = (h16)(x1.x * 0.125f); a[5] = (h16)(x1.y * 0.125f);
            a[6] = (h16)(x1.z * 0.125f); a[7] = (h16)(x1.w * 0.125f);
            aQ[kk] = a;
        }
    }

    __syncthreads();

    const float* Kbase = Kg + ((long)b * S_LEN * NHEAD + head) * HDIM;

    float m_r[4], l_r[4];
    f32x4 Oacc[4];
    #pragma unroll
    for (int r = 0; r < 4; ++r) { m_r[r] = -1e30f; l_r[r] = 0.f; }
    #pragma unroll
    for (int t = 0; t < 4; ++t) Oacc[t] = (f32x4){0.f,0.f,0.f,0.f};

    // wave wid needs window-rel keys [16*wid, 16*wid+272) -> 9 chunks from wid>>1
    const int c0 = wid >> 1;
    h16* Sw = &Slds[wid * 16 * SSTR];

    for (int i = 0; i < NCH; ++i) {
        const int kr0 = (c0 + i) * 32;

        // ---- S = Q K^T  (16q x 32k), K b-frag direct from global ----
        f32x4 s[2];
        #pragma unroll
        for (int t = 0; t < 2; ++t) {
            int kg  = kbase + kr0 + t*16 + l15;          // b-frag n = lane&15
            int kgc = kg < 0 ? 0 : (kg > S_LEN-1 ? S_LEN-1 : kg);
            const float* kp = Kbase + (long)kgc * rowstride;
            f32x4 acc = {0.f,0.f,0.f,0.f};
            #pragma unroll
            for (int kk = 0; kk < 2; ++kk) {
                float4 x0 = *(const float4*)(kp + kk*32 + quad*8);
                float4 x1 = *(const float4*)(kp + kk*32 + quad*8 + 4);
                f16x8 bK;
                bK[0]=(h16)x0.x; bK[1]=(h16)x0.y; bK[2]=(h16)x0.z; bK[3]=(h16)x0.w;
                bK[4]=(h16)x1.x; bK[5]=(h16)x1.y; bK[6]=(h16)x1.z; bK[7]=(h16)x1.w;
                acc = __builtin_amdgcn_mfma_f32_16x16x32_f16(aQ[kk], bK, acc, 0, 0, 0);
            }
            s[t] = acc;
        }

        // ---- mask + online softmax (per row r; rows = quad*4+r) ----
        const int col0 = kbase + kr0 + l15;
        const int col1 = col0 + 16;
        #pragma unroll
        for (int r = 0; r < 4; ++r) {
            const int qg = q0 + wid*16 + quad*4 + r;
            const int lo = (qg - WIN < 0) ? 0 : qg - WIN;
            const int hi = (qg + WIN > S_LEN-1) ? S_LEN-1 : qg + WIN;
            float s0 = (col0 >= lo && col0 <= hi) ? s[0][r] : -1e30f;
            float s1 = (col1 >= lo && col1 <= hi) ? s[1][r] : -1e30f;
            float cm = fmaxf(s0, s1);
            cm = fmaxf(cm, __shfl_xor(cm, 1));
            cm = fmaxf(cm, __shfl_xor(cm, 2));
            cm = fmaxf(cm, __shfl_xor(cm, 4));
            cm = fmaxf(cm, __shfl_xor(cm, 8));
            float mn    = fmaxf(m_r[r], cm);
            float alpha = __expf(m_r[r] - mn);   // exp(0)=1 in all-masked prefix: safe, V==0 there
            float p0 = __expf(s0 - mn);
            float p1 = __expf(s1 - mn);
            float ps = p0 + p1;
            ps += __shfl_xor(ps, 1);
            ps += __shfl_xor(ps, 2);
            ps += __shfl_xor(ps, 4);
            ps += __shfl_xor(ps, 8);
            l_r[r] = l_r[r] * alpha + ps;
            m_r[r] = mn;
            #pragma unroll
            for (int t = 0; t < 4; ++t) Oacc[t][r] *= alpha;
            // C-layout -> LDS (P tile 16x32)
            Sw[(quad*4 + r) * SSTR + l15]      = (h16)p0;
            Sw[(quad*4 + r) * SSTR + 16 + l15] = (h16)p1;
        }
        __syncthreads();

        // ---- O += P V : A-frag from LDS, b-frag = V^T row (contig 8 f16) ----
        f16x8 aP = *(const f16x8*)&Sw[l15 * SSTR + quad * 8];
        #pragma unroll
        for (int t = 0; t < 4; ++t) {
            f16x8 bV = *(const f16x8*)&Vlds[(t*16 + l15) * VSTR + kr0 + quad*8];
            Oacc[t] = __builtin_amdgcn_mfma_f32_16x16x32_f16(aP, bV, Oacc[t], 0, 0, 0);
        }
        __syncthreads();
    }

    // ---------------- epilogue: normalize + store (b, s, nh, h) -------------
    float* op = Og + ((long)(b * S_LEN + q0 + wid*16) * NHEAD + head) * HDIM;
    #pragma unroll
    for (int r = 0; r < 4; ++r) {
        float inv = 1.0f / l_r[r];
        #pragma unroll
        for (int t = 0; t < 4; ++t) {
            op[(quad*4 + r) * rowstride + t*16 + l15] = Oacc[t][r] * inv;
        }
    }
}

extern "C" void kernel_launch(void* const* d_in, const int* in_sizes, int n_in,
                              void* d_out, int out_size, void* d_ws, size_t ws_size,
                              hipStream_t stream) {
    const float* q = (const float*)d_in[0];
    const float* k = (const float*)d_in[1];
    const float* v = (const float*)d_in[2];
    float* out = (float*)d_out;
    const int batch = in_sizes[0] / (S_LEN * NHEAD * HDIM);
    dim3 grid(S_LEN / TQ, NHEAD, batch);
    wattn<<<grid, 512, 0, stream>>>(q, k, v, out);
}